// Round 3
// baseline (469.016 us; speedup 1.0000x reference)
//
#include <hip/hip_runtime.h>
#include <hip/hip_bf16.h>

// out[b,s,o] = sum_i x[b,s,i] * w[o,i]  -- NT GEMM M=8192, N=4096, K=4096
// w dequantized from 4-bit groups (256 vals/group, 16 groups per output row).

#define M_DIM 8192
#define N_DIM 4096
#define K_DIM 4096

typedef __bf16 bf16x8 __attribute__((ext_vector_type(8)));
typedef float f32x4 __attribute__((ext_vector_type(4)));
typedef unsigned short us8 __attribute__((ext_vector_type(8)));

__device__ __forceinline__ unsigned short f2bf_rne(float f) {
    unsigned int u = __builtin_bit_cast(unsigned int, f);
    u += 0x7FFFu + ((u >> 16) & 1u);
    return (unsigned short)(u >> 16);
}

// ---- fused prepass (unchanged) ---------------------------------------------
__global__ void prep_kernel(const float* __restrict__ x,
                            const int* __restrict__ packed,
                            const float* __restrict__ params,
                            ushort* __restrict__ a,
                            ushort* __restrict__ w) {
    int b = blockIdx.x;
    if (b < 16384) {
        int j = b * 256 + threadIdx.x;        // ushort8 index
        float4 v0 = ((const float4*)x)[2 * j];
        float4 v1 = ((const float4*)x)[2 * j + 1];
        us8 o;
        o[0] = f2bf_rne(v0.x); o[1] = f2bf_rne(v0.y);
        o[2] = f2bf_rne(v0.z); o[3] = f2bf_rne(v0.w);
        o[4] = f2bf_rne(v1.x); o[5] = f2bf_rne(v1.y);
        o[6] = f2bf_rne(v1.z); o[7] = f2bf_rne(v1.w);
        ((us8*)a)[j] = o;
    } else {
        int j = (b - 16384) * 256 + threadIdx.x;   // int4 index
        int4 v = ((const int4*)packed)[j];
        int g = j >> 5;                            // 4 ints same group
        float s = params[2 * g], z = params[2 * g + 1];
        unsigned int o0, o1, o2, o3;
        o0 = (unsigned int)f2bf_rne((float)(v.x & 15) * s + z)
           | ((unsigned int)f2bf_rne((float)((v.x >> 4) & 15) * s + z) << 16);
        o1 = (unsigned int)f2bf_rne((float)(v.y & 15) * s + z)
           | ((unsigned int)f2bf_rne((float)((v.y >> 4) & 15) * s + z) << 16);
        o2 = (unsigned int)f2bf_rne((float)(v.z & 15) * s + z)
           | ((unsigned int)f2bf_rne((float)((v.z >> 4) & 15) * s + z) << 16);
        o3 = (unsigned int)f2bf_rne((float)(v.w & 15) * s + z)
           | ((unsigned int)f2bf_rne((float)((v.w >> 4) & 15) * s + z) << 16);
        ((uint4*)w)[j] = make_uint4(o0, o1, o2, o3);
    }
}

// ---- main GEMM: 256x256, BK=64, pipelined, zero-VALU ds_read addressing ----
// Round-2 post-mortem: 58% MfmaUtil, VALUBusy 20% (per-tile address recompute),
// mid-barrier lgkm(0) drained freshly-issued reads, XCD swizzle fetched all of
// A per XCD (544 MB). Round-3 changes:
//  (a) 4 precomputed LDS base pointers; all 24 ds_reads/tile are base+imm
//      (buffer parity compile-time via x2 unroll) -> no per-tile VALU.
//  (b) Front-loaded A-reads: ph0 issues bf1+A(ph1)+A(ph2); ph1 issues NOTHING,
//      so mid-barrier lgkm(0) drains >=2-cluster-old reads (free). A(ph3) read
//      at ph2 (1-cluster cover before end drain). 3 A-sets (ph3 reuses ph1's).
//  (c) XCD swizzle A-panel-major: each XCD = 4 M-tiles x 16 N-tiles
//      (42 MB/XCD vs 71 MB), bx-fastest for temporal A-row L2 reuse.
// Schedule per tile t (buf = parity of t, compile-time):
//   [entering: A(ph0), bf0 in regs -- read under prev tile's MFMA_PH3]
//   ph0: read bf1,A1(ph1),A2(ph2); stageA(t+1,h0); MFMA_PH(0,A0)
//   ph1: stageA(t+1,h1); MFMA_PH(1,A1); lgkm(0)[free]; MID BARRIER
//   ph2: read A1(ph3); stageB(t+2,h0); MFMA_PH(2,A2)
//   ph3: stageB(t+2,h1); vmcnt(4)+lgkm(0); TILE BARRIER;
//        read bf0',A0' (t+1); MFMA_PH(3,A1)
// Ledger: outstanding at tile-end = B(t+1):4 + A(t+1):4 + B(t+2):4 = 12;
// vmcnt(4) -> A(t+1),B(t+1) landed, B(t+2) stays in flight (never drain to 0).
// WAR: B-slot(t) reads (bf0 prev-tile, bf1 ph0) lgkm-drained before MID
// barrier; stageB(t+2) (same parity slot) issues after it. A-slot(t) reads
// drained before TILE barrier; stageA(t+2) issues after it. RAW: each wave's
// vmcnt precedes the barrier -> all waves' stages landed before any crosses.
__global__ __launch_bounds__(512, 2) void gemm_bt(const ushort* __restrict__ A,
                                                  const ushort* __restrict__ B,
                                                  float* __restrict__ C) {
    __shared__ ushort lds[65536];   // 128 KiB: A slots [0,32768), B [32768,65536)

    const int tid  = threadIdx.x;
    const int w    = tid >> 6;           // wave 0..7
    const int lane = tid & 63;
    const int quad = lane >> 4;          // 0..3
    const int l16  = lane & 15;
    const int wm   = w >> 2;             // wave M index 0..1 (128 rows each)
    const int wn   = w & 3;              // wave N index 0..3 (64 cols each)

    // XCD swizzle, A-panel-major: xcd covers by in [xcd*4, xcd*4+4), all bx.
    const int bid = blockIdx.x;
    const int xcd = bid & 7;
    const int idx = bid >> 3;            // 0..63
    const int by  = xcd * 4 + (idx >> 4);
    const int bx  = idx & 15;
    const int m0  = by * 256;
    const int n0  = bx * 256;

    // staging source: thread t covers half-row (t>>3), pre-swizzled chunk
    const int srow = tid >> 3;                       // 0..63
    const int scol = ((tid & 7) ^ (srow & 7)) * 8;
    const ushort* aS = A + (size_t)(m0 + srow) * K_DIM + scol;
    const ushort* bS = B + (size_t)(n0 + srow) * K_DIM + scol;

    f32x4 acc[8][4] = {};
    bf16x8 afA0[2][2], afA1[2][2], afA2[2][2];  // A frag sets (A1 doubles ph3)
    bf16x8 bf0a[4], bf0b[4];                    // B ks=0, tile-parity ping-pong
    bf16x8 bf1[4];                              // B ks=1

    auto stageA = [&](int t, int h) {
        const int kc   = (t < 64 ? t : 63) * 64;
        const int slot = ((t & 1) * 2 + h) * 8192;
#pragma unroll
        for (int l = 0; l < 2; ++l)
            __builtin_amdgcn_global_load_lds(
                (const __attribute__((address_space(1))) void*)(aS + (size_t)(h * 128 + l * 64) * K_DIM + kc),
                (__attribute__((address_space(3))) void*)(lds + slot + (l * 512 + w * 64) * 8),
                16, 0, 0);
    };
    auto stageB = [&](int t, int h) {
        const int kc   = (t < 64 ? t : 63) * 64;
        const int slot = 32768 + ((t & 1) * 2 + h) * 8192;
#pragma unroll
        for (int l = 0; l < 2; ++l)
            __builtin_amdgcn_global_load_lds(
                (const __attribute__((address_space(1))) void*)(bS + (size_t)(h * 128 + l * 64) * K_DIM + kc),
                (__attribute__((address_space(3))) void*)(lds + slot + (l * 512 + w * 64) * 8),
                16, 0, 0);
    };

    // precomputed LDS bases: all frag reads are base + compile-time offset
    const int aBase = wm * 8192;                   // this wave's A half-slot
    const int bBase = 32768 + (wn >> 1) * 8192;    // this wave's B half-slot
    const int bR0   = (wn & 1) * 64;
    const int swz8  = l16 & 7;
    const int c0    = (quad ^ swz8) * 8;           // ks=0 chunk (elems)
    const int c1    = ((4 + quad) ^ swz8) * 8;     // ks=1 chunk
    const ushort* pA0 = lds + aBase + l16 * 64 + c0;
    const ushort* pA1 = lds + aBase + l16 * 64 + c1;
    const ushort* pB0 = lds + bBase + (bR0 + l16) * 64 + c0;
    const ushort* pB1 = lds + bBase + (bR0 + l16) * 64 + c1;

    // MFMA cluster for phase PH: output rows [PH*32, PH*32+32)
#define MFMA_PH(PH, AF, BF0)                                                   \
    do {                                                                       \
        __builtin_amdgcn_s_setprio(1);                                         \
        _Pragma("unroll")                                                      \
        for (int ii = 0; ii < 2; ++ii)                                         \
            _Pragma("unroll")                                                  \
            for (int j = 0; j < 4; ++j)                                        \
                acc[(PH) * 2 + ii][j] = __builtin_amdgcn_mfma_f32_16x16x32_bf16( \
                    AF[ii][0], BF0[j], acc[(PH) * 2 + ii][j], 0, 0, 0);        \
        _Pragma("unroll")                                                      \
        for (int ii = 0; ii < 2; ++ii)                                         \
            _Pragma("unroll")                                                  \
            for (int j = 0; j < 4; ++j)                                        \
                acc[(PH) * 2 + ii][j] = __builtin_amdgcn_mfma_f32_16x16x32_bf16( \
                    AF[ii][1], bf1[j], acc[(PH) * 2 + ii][j], 0, 0, 0);        \
        __builtin_amdgcn_s_setprio(0);                                         \
    } while (0)

// read one A frag set for phase PH from buffer BUF (both compile-time)
#define READ_A(DST, BUF, PH)                                                   \
    do {                                                                       \
        _Pragma("unroll")                                                      \
        for (int ii = 0; ii < 2; ++ii) {                                       \
            DST[ii][0] = *(const bf16x8*)(pA0 + (BUF) + ((PH) * 32 + ii * 16) * 64); \
            DST[ii][1] = *(const bf16x8*)(pA1 + (BUF) + ((PH) * 32 + ii * 16) * 64); \
        }                                                                      \
    } while (0)
#define READ_B0(DST, BUF)                                                      \
    do {                                                                       \
        _Pragma("unroll")                                                      \
        for (int j = 0; j < 4; ++j)                                            \
            DST[j] = *(const bf16x8*)(pB0 + (BUF) + j * 1024);                 \
    } while (0)
#define READ_B1(BUF)                                                           \
    do {                                                                       \
        _Pragma("unroll")                                                      \
        for (int j = 0; j < 4; ++j)                                            \
            bf1[j] = *(const bf16x8*)(pB1 + (BUF) + j * 1024);                 \
    } while (0)

    // prologue: stage B0,A0,B1 (12 loads); drain to 4 (B1 in flight); barrier;
    // first-tile ph0 frag reads.
    stageB(0, 0); stageB(0, 1); stageA(0, 0); stageA(0, 1); stageB(1, 0); stageB(1, 1);
    asm volatile("s_waitcnt vmcnt(4)" ::: "memory");
    __builtin_amdgcn_s_barrier();
    asm volatile("" ::: "memory");
    READ_B0(bf0a, 0);
    READ_A(afA0, 0, 0);

#define TILE(T, BUF, NBUF, BF0C, BF0N)                                         \
    do {                                                                       \
        const int t = (T);                                                     \
        /* ph0: front-load reads */                                            \
        READ_B1(BUF);                                                          \
        READ_A(afA1, BUF, 1);                                                  \
        READ_A(afA2, BUF, 2);                                                  \
        stageA(t + 1, 0);                                                      \
        MFMA_PH(0, afA0, BF0C);                                                \
        /* ph1: no new reads -> mid drain is free */                           \
        stageA(t + 1, 1);                                                      \
        MFMA_PH(1, afA1, BF0C);                                                \
        asm volatile("s_waitcnt lgkmcnt(0)" ::: "memory");                     \
        __builtin_amdgcn_sched_barrier(0);                                     \
        __builtin_amdgcn_s_barrier();       /* mid: B-slot(t) free */          \
        asm volatile("" ::: "memory");                                         \
        /* ph2 */                                                              \
        READ_A(afA1, BUF, 3);               /* ph3 reuses A1 regs */           \
        stageB(t + 2, 0);                                                      \
        MFMA_PH(2, afA2, BF0C);                                                \
        /* ph3 */                                                              \
        stageB(t + 2, 1);                                                      \
        asm volatile("s_waitcnt vmcnt(4) lgkmcnt(0)" ::: "memory");            \
        __builtin_amdgcn_s_barrier();       /* tile: buf(t+1) ready */         \
        asm volatile("" ::: "memory");                                         \
        if (t < 63) { READ_B0(BF0N, NBUF); READ_A(afA0, NBUF, 0); }            \
        __builtin_amdgcn_sched_barrier(0);                                     \
        MFMA_PH(3, afA1, BF0C);                                                \
    } while (0)

#pragma unroll 1
    for (int tt = 0; tt < 64; tt += 2) {
        TILE(tt,     0,     16384, bf0a, bf0b);
        TILE(tt + 1, 16384, 0,     bf0b, bf0a);
    }
#undef TILE
#undef MFMA_PH
#undef READ_A
#undef READ_B0
#undef READ_B1

    // epilogue: C/D layout col=lane&15, row=quad*4+reg (m89/m91-verified)
    const int crow = m0 + wm * 128 + quad * 4;
    const int ccol = n0 + wn * 64 + l16;
#pragma unroll
    for (int rf = 0; rf < 8; ++rf)
#pragma unroll
        for (int j = 0; j < 4; ++j)
#pragma unroll
            for (int r = 0; r < 4; ++r)
                C[(size_t)(crow + rf * 16 + r) * N_DIM + ccol + j * 16] = acc[rf][j][r];
}

// ---- emergency fallback (only if ws too small) ------------------------------
__global__ void naive_kernel(const float* __restrict__ x, const int* __restrict__ packed,
                             const float* __restrict__ params, float* __restrict__ out) {
    int idx = blockIdx.x * blockDim.x + threadIdx.x;
    if (idx >= M_DIM * N_DIM) return;
    int m = idx / N_DIM, o = idx % N_DIM;
    const float* xr = x + (size_t)m * K_DIM;
    float sum = 0.f;
    for (int gi = 0; gi < K_DIM / 256; ++gi) {
        int g = o * (K_DIM / 256) + gi;
        float s = params[2 * g], z = params[2 * g + 1];
        const int* p = packed + (size_t)g * 128;
        const float* xx = xr + gi * 256;
        for (int j = 0; j < 128; ++j) {
            int v = p[j];
            sum += xx[2 * j]     * ((float)(v & 15) * s + z);
            sum += xx[2 * j + 1] * ((float)((v >> 4) & 15) * s + z);
        }
    }
    out[idx] = sum;
}

extern "C" void kernel_launch(void* const* d_in, const int* in_sizes, int n_in,
                              void* d_out, int out_size, void* d_ws, size_t ws_size,
                              hipStream_t stream) {
    const float* x      = (const float*)d_in[0];
    const int*   packed = (const int*)d_in[1];
    const float* params = (const float*)d_in[2];
    float* out = (float*)d_out;

    const size_t a_bytes = (size_t)M_DIM * K_DIM * 2;   // 67.1 MB bf16 x
    const size_t w_bytes = (size_t)N_DIM * K_DIM * 2;   // 33.6 MB bf16 W

    if (ws_size >= a_bytes + w_bytes) {
        ushort* Abf = (ushort*)d_ws;
        ushort* Wbf = (ushort*)((char*)d_ws + a_bytes);

        prep_kernel<<<24576, 256, 0, stream>>>(x, packed, params, Abf, Wbf);

        // 32 M-tiles x 16 N-tiles = 512 blocks, XCD-swizzled inside kernel
        gemm_bt<<<512, 512, 0, stream>>>(Abf, Wbf, out);
    } else {
        int n = M_DIM * N_DIM;
        naive_kernel<<<(n + 255) / 256, 256, 0, stream>>>(x, packed, params, out);
    }
}

// Round 4
// 455.936 us; speedup vs baseline: 1.0287x; 1.0287x over previous
//
#include <hip/hip_runtime.h>
#include <hip/hip_bf16.h>

// out[b,s,o] = sum_i x[b,s,i] * w[o,i]  -- NT GEMM M=8192, N=4096, K=4096
// w dequantized from 4-bit groups (256 vals/group, 16 groups per output row).

#define M_DIM 8192
#define N_DIM 4096
#define K_DIM 4096

typedef __bf16 bf16x8 __attribute__((ext_vector_type(8)));
typedef float f32x4 __attribute__((ext_vector_type(4)));
typedef unsigned short us8 __attribute__((ext_vector_type(8)));

__device__ __forceinline__ unsigned short f2bf_rne(float f) {
    unsigned int u = __builtin_bit_cast(unsigned int, f);
    u += 0x7FFFu + ((u >> 16) & 1u);
    return (unsigned short)(u >> 16);
}

// ---- fused prepass (unchanged) ---------------------------------------------
__global__ void prep_kernel(const float* __restrict__ x,
                            const int* __restrict__ packed,
                            const float* __restrict__ params,
                            ushort* __restrict__ a,
                            ushort* __restrict__ w) {
    int b = blockIdx.x;
    if (b < 16384) {
        int j = b * 256 + threadIdx.x;        // ushort8 index
        float4 v0 = ((const float4*)x)[2 * j];
        float4 v1 = ((const float4*)x)[2 * j + 1];
        us8 o;
        o[0] = f2bf_rne(v0.x); o[1] = f2bf_rne(v0.y);
        o[2] = f2bf_rne(v0.z); o[3] = f2bf_rne(v0.w);
        o[4] = f2bf_rne(v1.x); o[5] = f2bf_rne(v1.y);
        o[6] = f2bf_rne(v1.z); o[7] = f2bf_rne(v1.w);
        ((us8*)a)[j] = o;
    } else {
        int j = (b - 16384) * 256 + threadIdx.x;   // int4 index
        int4 v = ((const int4*)packed)[j];
        int g = j >> 5;                            // 4 ints same group
        float s = params[2 * g], z = params[2 * g + 1];
        unsigned int o0, o1, o2, o3;
        o0 = (unsigned int)f2bf_rne((float)(v.x & 15) * s + z)
           | ((unsigned int)f2bf_rne((float)((v.x >> 4) & 15) * s + z) << 16);
        o1 = (unsigned int)f2bf_rne((float)(v.y & 15) * s + z)
           | ((unsigned int)f2bf_rne((float)((v.y >> 4) & 15) * s + z) << 16);
        o2 = (unsigned int)f2bf_rne((float)(v.z & 15) * s + z)
           | ((unsigned int)f2bf_rne((float)((v.z >> 4) & 15) * s + z) << 16);
        o3 = (unsigned int)f2bf_rne((float)(v.w & 15) * s + z)
           | ((unsigned int)f2bf_rne((float)((v.w >> 4) & 15) * s + z) << 16);
        ((uint4*)w)[j] = make_uint4(o0, o1, o2, o3);
    }
}

// ---- main GEMM: 256x256, BK=64 -- EXACT round-2 structure (proven 220us) ---
// plus two isolated, analytically-safe changes:
//  (a) zero-VALU ds_read addressing: 4 precomputed base pointers, every
//      frag read = base + compile-time immediate (buffer parity via x2 unroll).
//  (b) mid-barrier drain lgkmcnt(8), not 0: at that point the only pending DS
//      ops are the 8 just-issued afA(ph2) reads, which target the A-slot --
//      NOT the B-slot this barrier protects. LDS returns are IN-ORDER, so
//      outstanding<=8 guarantees all older reads (bf1/bf0, the B-slot reads)
//      retired. The 8 A-reads drain under ph2's MFMA instead of stalling the
//      whole CU on a cold LDS port before the barrier.
// Schedule per tile t (buf = parity of t, compile-time):
//   [entering: afA(ph0), bf0 in regs -- read under prev tile's MFMA_PH3]
//   ph0: read bf1, afB(ph1); stageA(t+1,h0); MFMA_PH(0, afA)
//   ph1: read afA(ph2);      stageA(t+1,h1); MFMA_PH(1, afB);
//        lgkmcnt(8); MID BARRIER            <- frees B-slot(t)
//   ph2: read afB(ph3);      stageB(t+2,h0); MFMA_PH(2, afA)
//   ph3:                     stageB(t+2,h1); vmcnt(4)+lgkmcnt(0); TILE BARRIER
//        read bf0', afA'(t+1, ph0);  MFMA_PH(3, afB)
// vmcnt ledger: outstanding at tile drain = B(t+1):4 + A(t+1):4 + B(t+2):4
// = 12 -> vmcnt(4) retires B(t+1),A(t+1), leaves B(t+2) in flight (never 0).
// WAR: B-slot reads drained before MID (in-order lgkm<=8); A-slot reads
// (afB ph3) drained by lgkmcnt(0) at TILE barrier, and stageA(t+2) only
// issues after it. RAW: every wave's own vmcnt precedes the barrier.
__global__ __launch_bounds__(512, 2) void gemm_bt(const ushort* __restrict__ A,
                                                  const ushort* __restrict__ B,
                                                  float* __restrict__ C) {
    __shared__ ushort lds[65536];   // 128 KiB: A slots [0,32768), B [32768,65536)

    const int tid  = threadIdx.x;
    const int w    = tid >> 6;           // wave 0..7
    const int lane = tid & 63;
    const int quad = lane >> 4;          // 0..3
    const int l16  = lane & 15;
    const int wm   = w >> 2;             // wave M index 0..1 (128 rows each)
    const int wn   = w & 3;              // wave N index 0..3 (64 cols each)

    // XCD-bijective swizzle (round-2 proven): 64 contiguous per XCD,
    // B-panel-major: one XCD covers 2 N-columns, by-fastest.
    const int bid = blockIdx.x;
    const int sid = (bid & 7) * 64 + (bid >> 3);
    const int by  = sid & 31;            // M tile 0..31
    const int bx  = sid >> 5;            // N tile 0..15
    const int m0  = by * 256;
    const int n0  = bx * 256;

    // staging source: thread t covers half-row (t>>3), pre-swizzled chunk
    const int srow = tid >> 3;                       // 0..63
    const int scol = ((tid & 7) ^ (srow & 7)) * 8;
    const ushort* aS = A + (size_t)(m0 + srow) * K_DIM + scol;
    const ushort* bS = B + (size_t)(n0 + srow) * K_DIM + scol;

    f32x4 acc[8][4] = {};
    bf16x8 afA[2][2], afB[2][2];         // A frags, phase ping-pong (r2 layout)
    bf16x8 bf0a[4], bf0b[4];             // B ks=0 frags, tile-parity ping-pong
    bf16x8 bf1[4];                       // B ks=1 frags

    auto stageA = [&](int t, int h) {
        const int kc   = (t < 64 ? t : 63) * 64;
        const int slot = ((t & 1) * 2 + h) * 8192;
#pragma unroll
        for (int l = 0; l < 2; ++l)
            __builtin_amdgcn_global_load_lds(
                (const __attribute__((address_space(1))) void*)(aS + (size_t)(h * 128 + l * 64) * K_DIM + kc),
                (__attribute__((address_space(3))) void*)(lds + slot + (l * 512 + w * 64) * 8),
                16, 0, 0);
    };
    auto stageB = [&](int t, int h) {
        const int kc   = (t < 64 ? t : 63) * 64;
        const int slot = 32768 + ((t & 1) * 2 + h) * 8192;
#pragma unroll
        for (int l = 0; l < 2; ++l)
            __builtin_amdgcn_global_load_lds(
                (const __attribute__((address_space(1))) void*)(bS + (size_t)(h * 128 + l * 64) * K_DIM + kc),
                (__attribute__((address_space(3))) void*)(lds + slot + (l * 512 + w * 64) * 8),
                16, 0, 0);
    };

    // precomputed LDS bases: all frag reads are base + compile-time offset
    const int aBase = wm * 8192;                   // this wave's A half-slot
    const int bBase = 32768 + (wn >> 1) * 8192;    // this wave's B half-slot
    const int bR0   = (wn & 1) * 64;
    const int swz8  = l16 & 7;
    const int c0    = (quad ^ swz8) * 8;           // ks=0 chunk (elems)
    const int c1    = ((4 + quad) ^ swz8) * 8;     // ks=1 chunk
    const ushort* pA0 = lds + aBase + l16 * 64 + c0;
    const ushort* pA1 = lds + aBase + l16 * 64 + c1;
    const ushort* pB0 = lds + bBase + (bR0 + l16) * 64 + c0;
    const ushort* pB1 = lds + bBase + (bR0 + l16) * 64 + c1;

    // MFMA cluster for phase PH: output rows [PH*32, PH*32+32)
#define MFMA_PH(PH, AF, BF0)                                                   \
    do {                                                                       \
        __builtin_amdgcn_s_setprio(1);                                         \
        _Pragma("unroll")                                                      \
        for (int ii = 0; ii < 2; ++ii)                                         \
            _Pragma("unroll")                                                  \
            for (int j = 0; j < 4; ++j)                                        \
                acc[(PH) * 2 + ii][j] = __builtin_amdgcn_mfma_f32_16x16x32_bf16( \
                    AF[ii][0], BF0[j], acc[(PH) * 2 + ii][j], 0, 0, 0);        \
        _Pragma("unroll")                                                      \
        for (int ii = 0; ii < 2; ++ii)                                         \
            _Pragma("unroll")                                                  \
            for (int j = 0; j < 4; ++j)                                        \
                acc[(PH) * 2 + ii][j] = __builtin_amdgcn_mfma_f32_16x16x32_bf16( \
                    AF[ii][1], bf1[j], acc[(PH) * 2 + ii][j], 0, 0, 0);        \
        __builtin_amdgcn_s_setprio(0);                                         \
    } while (0)

// frag reads: base pointer + compile-time immediate only
#define READ_A(DST, BUF, PH)                                                   \
    do {                                                                       \
        _Pragma("unroll")                                                      \
        for (int ii = 0; ii < 2; ++ii) {                                       \
            DST[ii][0] = *(const bf16x8*)(pA0 + (BUF) + ((PH) * 32 + ii * 16) * 64); \
            DST[ii][1] = *(const bf16x8*)(pA1 + (BUF) + ((PH) * 32 + ii * 16) * 64); \
        }                                                                      \
    } while (0)
#define READ_B0(DST, BUF)                                                      \
    do {                                                                       \
        _Pragma("unroll")                                                      \
        for (int j = 0; j < 4; ++j)                                            \
            DST[j] = *(const bf16x8*)(pB0 + (BUF) + j * 1024);                 \
    } while (0)
#define READ_B1(BUF)                                                           \
    do {                                                                       \
        _Pragma("unroll")                                                      \
        for (int j = 0; j < 4; ++j)                                            \
            bf1[j] = *(const bf16x8*)(pB1 + (BUF) + j * 1024);                 \
    } while (0)

    // prologue: stage B0,A0,B1 (12 loads); drain to 4 (B1 in flight); barrier;
    // first-tile ph0 frag reads (one-time exposed burst).
    stageB(0, 0); stageB(0, 1); stageA(0, 0); stageA(0, 1); stageB(1, 0); stageB(1, 1);
    asm volatile("s_waitcnt vmcnt(4)" ::: "memory");
    __builtin_amdgcn_s_barrier();
    asm volatile("" ::: "memory");
    READ_B0(bf0a, 0);
    READ_A(afA, 0, 0);

#define TILE(T, BUF, NBUF, BF0C, BF0N)                                         \
    do {                                                                       \
        const int t = (T);                                                     \
        /* ph0 */                                                              \
        READ_B1(BUF);                                                          \
        READ_A(afB, BUF, 1);                                                   \
        stageA(t + 1, 0);                                                      \
        MFMA_PH(0, afA, BF0C);                                                 \
        /* ph1 */                                                              \
        READ_A(afA, BUF, 2);                                                   \
        stageA(t + 1, 1);                                                      \
        MFMA_PH(1, afB, BF0C);                                                 \
        asm volatile("s_waitcnt lgkmcnt(8)" ::: "memory");  /* B-slot reads   */\
        __builtin_amdgcn_sched_barrier(0);                  /* done (in-order) */\
        __builtin_amdgcn_s_barrier();       /* mid: B-slot(t) free */          \
        asm volatile("" ::: "memory");                                         \
        /* ph2 */                                                              \
        READ_A(afB, BUF, 3);                                                   \
        stageB(t + 2, 0);                                                      \
        MFMA_PH(2, afA, BF0C);                                                 \
        /* ph3 */                                                              \
        stageB(t + 2, 1);                                                      \
        asm volatile("s_waitcnt vmcnt(4) lgkmcnt(0)" ::: "memory");            \
        __builtin_amdgcn_s_barrier();       /* tile: buf(t+1) ready */         \
        asm volatile("" ::: "memory");                                         \
        if (t < 63) { READ_B0(BF0N, NBUF); READ_A(afA, NBUF, 0); }             \
        __builtin_amdgcn_sched_barrier(0);                                     \
        MFMA_PH(3, afB, BF0C);                                                 \
    } while (0)

#pragma unroll 1
    for (int tt = 0; tt < 64; tt += 2) {
        TILE(tt,     0,     16384, bf0a, bf0b);
        TILE(tt + 1, 16384, 0,     bf0b, bf0a);
    }
#undef TILE
#undef MFMA_PH
#undef READ_A
#undef READ_B0
#undef READ_B1

    // epilogue: C/D layout col=lane&15, row=quad*4+reg (m89/m91-verified)
    const int crow = m0 + wm * 128 + quad * 4;
    const int ccol = n0 + wn * 64 + l16;
#pragma unroll
    for (int rf = 0; rf < 8; ++rf)
#pragma unroll
        for (int j = 0; j < 4; ++j)
#pragma unroll
            for (int r = 0; r < 4; ++r)
                C[(size_t)(crow + rf * 16 + r) * N_DIM + ccol + j * 16] = acc[rf][j][r];
}

// ---- emergency fallback (only if ws too small) ------------------------------
__global__ void naive_kernel(const float* __restrict__ x, const int* __restrict__ packed,
                             const float* __restrict__ params, float* __restrict__ out) {
    int idx = blockIdx.x * blockDim.x + threadIdx.x;
    if (idx >= M_DIM * N_DIM) return;
    int m = idx / N_DIM, o = idx % N_DIM;
    const float* xr = x + (size_t)m * K_DIM;
    float sum = 0.f;
    for (int gi = 0; gi < K_DIM / 256; ++gi) {
        int g = o * (K_DIM / 256) + gi;
        float s = params[2 * g], z = params[2 * g + 1];
        const int* p = packed + (size_t)g * 128;
        const float* xx = xr + gi * 256;
        for (int j = 0; j < 128; ++j) {
            int v = p[j];
            sum += xx[2 * j]     * ((float)(v & 15) * s + z);
            sum += xx[2 * j + 1] * ((float)((v >> 4) & 15) * s + z);
        }
    }
    out[idx] = sum;
}

extern "C" void kernel_launch(void* const* d_in, const int* in_sizes, int n_in,
                              void* d_out, int out_size, void* d_ws, size_t ws_size,
                              hipStream_t stream) {
    const float* x      = (const float*)d_in[0];
    const int*   packed = (const int*)d_in[1];
    const float* params = (const float*)d_in[2];
    float* out = (float*)d_out;

    const size_t a_bytes = (size_t)M_DIM * K_DIM * 2;   // 67.1 MB bf16 x
    const size_t w_bytes = (size_t)N_DIM * K_DIM * 2;   // 33.6 MB bf16 W

    if (ws_size >= a_bytes + w_bytes) {
        ushort* Abf = (ushort*)d_ws;
        ushort* Wbf = (ushort*)((char*)d_ws + a_bytes);

        prep_kernel<<<24576, 256, 0, stream>>>(x, packed, params, Abf, Wbf);

        // 32 M-tiles x 16 N-tiles = 512 blocks, XCD-swizzled inside kernel
        gemm_bt<<<512, 512, 0, stream>>>(Abf, Wbf, out);
    } else {
        int n = M_DIM * N_DIM;
        naive_kernel<<<(n + 255) / 256, 256, 0, stream>>>(x, packed, params, out);
    }
}